// Round 1
// baseline (1269.565 us; speedup 1.0000x reference)
//
#include <hip/hip_runtime.h>
#include <hip/hip_bf16.h>

#define FEAT 40960
#define NH1  256
#define MAXNZ 128   // reference guarantees <=30 nonzeros/row; guard anyway

typedef float vfloat4 __attribute__((ext_vector_type(4)));
typedef int   vint4   __attribute__((ext_vector_type(4)));

// ---------------------------------------------------------------------------
// Kernel A: transpose ft_w [256][40960] -> ft_wt [40960][256]
// ---------------------------------------------------------------------------
__global__ __launch_bounds__(256) void transpose_ftw(const float* __restrict__ ft_w,
                                                     float* __restrict__ ft_wt) {
    __shared__ float tile[32][33];           // +1 pad: no bank conflicts
    const int i0 = blockIdx.x * 32;          // feature dim
    const int h0 = blockIdx.y * 32;          // hidden dim
    const int tx = threadIdx.x;              // 0..31
    const int ty = threadIdx.y;              // 0..7
#pragma unroll
    for (int j = 0; j < 4; ++j) {
        tile[ty + j * 8][tx] = ft_w[(size_t)(h0 + ty + j * 8) * FEAT + i0 + tx];
    }
    __syncthreads();
#pragma unroll
    for (int j = 0; j < 4; ++j) {
        ft_wt[(size_t)(i0 + ty + j * 8) * NH1 + h0 + tx] = tile[tx][ty + j * 8];
    }
}

// ---------------------------------------------------------------------------
// Kernel B: fully fused NNUE forward, one 256-thread block per batch row.
// (Round-4 structure. This round: scan stage register-double-buffered,
//  cached (non-NT) loads, integer-OR nonzero detection. Gather/MLP unchanged.)
// ---------------------------------------------------------------------------
__global__ __launch_bounds__(256) void nnue_fused(
    const float* __restrict__ wf,     // [B][40960]
    const float* __restrict__ bfeat,  // [B][40960]
    const float* __restrict__ ft_wt,  // [40960][256] transposed
    const float* __restrict__ ft_b,   // [256]
    const float* __restrict__ fc1_w,  // [32][512]
    const float* __restrict__ fc1_b,  // [32]
    const float* __restrict__ fc2_w,  // [32][32]
    const float* __restrict__ fc2_b,  // [32]
    const float* __restrict__ fc3_w,  // [1][32]
    const float* __restrict__ fc3_b,  // [1]
    float* __restrict__ out)          // [B]
{
    __shared__ int   idxw[MAXNZ], idxb[MAXNZ];
    __shared__ float valw[MAXNZ], valb[MAXNZ];
    __shared__ int   cntw, cntb;
    __shared__ float xsh[512];
    __shared__ float red[256];
    __shared__ float h1[32], h2[32];

    const int tid = threadIdx.x;
    const int b   = blockIdx.x;

    if (tid == 0) { cntw = 0; cntb = 0; }
    // hoist the (tiny) bias load so it overlaps the scan
    const float ftb = ft_b[tid];
    __syncthreads();

    // ---- Stage 1: scan both feature rows, compact nonzeros into LDS lists.
    // Register double-buffer at group granularity: the NEXT group's 8 dwordx4
    // loads are issued before the current group's value-dependent tests, so
    // ~128 B/thread stay in flight across the branchy append region.
    // Integer bit-pattern nonzero test is exact (inputs are {0.0f, 1.0f}).
    const vint4* wf4 = (const vint4*)(wf    + (size_t)b * FEAT);
    const vint4* bf4 = (const vint4*)(bfeat + (size_t)b * FEAT);
    constexpr int ITERS = FEAT / 4 / 256;  // 40
    constexpr int GRP   = 4;
    constexpr int NGRP  = ITERS / GRP;     // 10

    vint4 cw[GRP], cb[GRP], nw_[GRP], nb_[GRP];
#pragma unroll
    for (int p = 0; p < GRP; ++p) {
        cw[p] = wf4[p * 256 + tid];
        cb[p] = bf4[p * 256 + tid];
    }
    for (int g = 0; g < NGRP; ++g) {
        if (g + 1 < NGRP) {
#pragma unroll
            for (int p = 0; p < GRP; ++p) {
                nw_[p] = wf4[((g + 1) * GRP + p) * 256 + tid];
                nb_[p] = bf4[((g + 1) * GRP + p) * 256 + tid];
            }
        }
#pragma unroll
        for (int p = 0; p < GRP; ++p) {
            const int base = ((g * GRP + p) * 256 + tid) * 4;
            const vint4 vw = cw[p];
            if (__any((vw.x | vw.y | vw.z | vw.w) != 0)) {
                if (vw.x) { int q = atomicAdd(&cntw, 1); if (q < MAXNZ) { idxw[q] = base + 0; valw[q] = __int_as_float(vw.x); } }
                if (vw.y) { int q = atomicAdd(&cntw, 1); if (q < MAXNZ) { idxw[q] = base + 1; valw[q] = __int_as_float(vw.y); } }
                if (vw.z) { int q = atomicAdd(&cntw, 1); if (q < MAXNZ) { idxw[q] = base + 2; valw[q] = __int_as_float(vw.z); } }
                if (vw.w) { int q = atomicAdd(&cntw, 1); if (q < MAXNZ) { idxw[q] = base + 3; valw[q] = __int_as_float(vw.w); } }
            }
            const vint4 vb = cb[p];
            if (__any((vb.x | vb.y | vb.z | vb.w) != 0)) {
                if (vb.x) { int q = atomicAdd(&cntb, 1); if (q < MAXNZ) { idxb[q] = base + 0; valb[q] = __int_as_float(vb.x); } }
                if (vb.y) { int q = atomicAdd(&cntb, 1); if (q < MAXNZ) { idxb[q] = base + 1; valb[q] = __int_as_float(vb.y); } }
                if (vb.z) { int q = atomicAdd(&cntb, 1); if (q < MAXNZ) { idxb[q] = base + 2; valb[q] = __int_as_float(vb.z); } }
                if (vb.w) { int q = atomicAdd(&cntb, 1); if (q < MAXNZ) { idxb[q] = base + 3; valb[q] = __int_as_float(vb.w); } }
            }
        }
        if (g + 1 < NGRP) {
#pragma unroll
            for (int p = 0; p < GRP; ++p) { cw[p] = nw_[p]; cb[p] = nb_[p]; }
        }
    }
    __syncthreads();
    const int nw = min(cntw, MAXNZ);
    const int nb = min(cntb, MAXNZ);

    // ---- Stage 2: gather-sum into hidden unit tid. Interleave white/black
    // with 2-way unroll each: 4 outstanding L2/L3 loads per thread.
    float aw0 = ftb, aw1 = 0.f;
    float ab0 = ftb, ab1 = 0.f;
    const int nmin = min(nw, nb);
    int j = 0;
    for (; j + 2 <= nmin; j += 2) {
        const float w0 = ft_wt[(size_t)idxw[j]     * NH1 + tid];
        const float w1 = ft_wt[(size_t)idxw[j + 1] * NH1 + tid];
        const float b0 = ft_wt[(size_t)idxb[j]     * NH1 + tid];
        const float b1 = ft_wt[(size_t)idxb[j + 1] * NH1 + tid];
        aw0 += valw[j] * w0;  aw1 += valw[j + 1] * w1;
        ab0 += valb[j] * b0;  ab1 += valb[j + 1] * b1;
    }
    for (int jw = j; jw < nw; ++jw) aw0 += valw[jw] * ft_wt[(size_t)idxw[jw] * NH1 + tid];
    for (int jb = j; jb < nb; ++jb) ab0 += valb[jb] * ft_wt[(size_t)idxb[jb] * NH1 + tid];

    xsh[tid]       = fminf(fmaxf(aw0 + aw1, 0.f), 1.f);
    xsh[256 + tid] = fminf(fmaxf(ab0 + ab1, 0.f), 1.f);
    __syncthreads();

    // ---- Stage 3: fc1 (512 -> 32), 8 partial-threads per output
    {
        const int o = tid & 31, part = tid >> 5;
        const float* wrow = fc1_w + o * 512 + part * 64;
        const float* xp   = xsh + part * 64;
        float s = 0.f;
#pragma unroll
        for (int k = 0; k < 64; ++k) s += wrow[k] * xp[k];
        red[tid] = s;
    }
    __syncthreads();
    if (tid < 32) {
        float s = fc1_b[tid];
#pragma unroll
        for (int p = 0; p < 8; ++p) s += red[tid + p * 32];
        h1[tid] = fminf(fmaxf(s, 0.f), 1.f);
    }
    __syncthreads();

    // ---- Stage 4: fc2 (32 -> 32)
    if (tid < 32) {
        float s = fc2_b[tid];
#pragma unroll
        for (int k = 0; k < 32; ++k) s += fc2_w[tid * 32 + k] * h1[k];
        h2[tid] = fminf(fmaxf(s, 0.f), 1.f);
    }
    __syncthreads();

    // ---- Stage 5: fc3 (32 -> 1)
    if (tid == 0) {
        float s = fc3_b[0];
#pragma unroll
        for (int k = 0; k < 32; ++k) s += fc3_w[k] * h2[k];
        out[b] = s;
    }
}

// ---------------------------------------------------------------------------
extern "C" void kernel_launch(void* const* d_in, const int* in_sizes, int n_in,
                              void* d_out, int out_size, void* d_ws, size_t ws_size,
                              hipStream_t stream) {
    const float* wf    = (const float*)d_in[0];
    const float* bfeat = (const float*)d_in[1];
    const float* ft_w  = (const float*)d_in[2];
    const float* ft_b  = (const float*)d_in[3];
    const float* fc1_w = (const float*)d_in[4];
    const float* fc1_b = (const float*)d_in[5];
    const float* fc2_w = (const float*)d_in[6];
    const float* fc2_b = (const float*)d_in[7];
    const float* fc3_w = (const float*)d_in[8];
    const float* fc3_b = (const float*)d_in[9];
    float* out = (float*)d_out;

    const int B = in_sizes[0] / FEAT;  // 4096
    float* ft_wt = (float*)d_ws;       // 42 MB of the ~2.7 GB ws

    {
        dim3 blk(32, 8);
        dim3 grd(FEAT / 32, NH1 / 32);
        transpose_ftw<<<grd, blk, 0, stream>>>(ft_w, ft_wt);
    }
    nnue_fused<<<B, 256, 0, stream>>>(wf, bfeat, ft_wt,
                                      ft_b, fc1_w, fc1_b, fc2_w, fc2_b,
                                      fc3_w, fc3_b, out);
}